// Round 4
// baseline (533.889 us; speedup 1.0000x reference)
//
#include <hip/hip_runtime.h>
#include <hip/hip_bf16.h>
#include <stdint.h>

#define TOKENS 8192
#define HD     2048
#define NE     8
#define NP     28      // unordered expert pairs (8 choose 2)
#define PCAP   8192    // bucket capacity (total entries across pairs = 8192)

typedef __attribute__((ext_vector_type(8)))  short short8;
typedef __attribute__((ext_vector_type(8)))  unsigned short ushort8v;
typedef __attribute__((ext_vector_type(16))) float f32x16;

// pair p -> (expert a, expert b), a<b; p = a*(13-a)/2 + b - 1
__constant__ int d_pa[NP] = {0,0,0,0,0,0,0,1,1,1,1,1,1,2,2,2,2,2,3,3,3,3,4,4,4,5,5,6};
__constant__ int d_pb[NP] = {1,2,3,4,5,6,7,2,3,4,5,6,7,3,4,5,6,7,4,5,6,7,5,6,7,6,7,7};

__device__ __forceinline__ unsigned short f2bf_rne(float f) {
  union { float f; unsigned u; } v; v.f = f;
  unsigned u = v.u;
  return (unsigned short)((u + 0x7fffu + ((u >> 16) & 1u)) >> 16);
}

__device__ __forceinline__ void async_load16(const void* g, void* lds) {
  __builtin_amdgcn_global_load_lds(
      (const __attribute__((address_space(1))) unsigned int*)g,
      (__attribute__((address_space(3))) unsigned int*)lds, 16, 0, 0);
}

// ---------------------------------------------------------------- prep
// blocks 0..2047: router (wave/token fp32 logits + x->bf16 + PAIR bucketing,
// ONE atomic per token over 28 spread counters). blocks 2048..6143: W fp32->
// bf16 convert. counts[] zeroed by hipMemsetAsync before this dispatch.
__global__ __launch_bounds__(256) void prep_kernel(
    const float* __restrict__ x, const float* __restrict__ gw,
    const float* __restrict__ ew, unsigned short* __restrict__ xb,
    unsigned short* __restrict__ wb, float* __restrict__ logits_out,
    int* __restrict__ counts, int* __restrict__ btok,
    float2* __restrict__ bw2) {
  if (blockIdx.x >= 2048) {
    // ---- convert W: 4 iters/thread over 4,194,304 ushort8 units
    int i = (blockIdx.x - 2048) * 256 + threadIdx.x;
    const int n8 = NE * HD * HD / 8;
    const int stride = 4096 * 256;
    const float4* s4 = (const float4*)ew;
    ushort8v* d8 = (ushort8v*)wb;
    for (; i < n8; i += stride) {
      float4 a = s4[i * 2], b = s4[i * 2 + 1];
      ushort8v o;
      o[0] = f2bf_rne(a.x); o[1] = f2bf_rne(a.y);
      o[2] = f2bf_rne(a.z); o[3] = f2bf_rne(a.w);
      o[4] = f2bf_rne(b.x); o[5] = f2bf_rne(b.y);
      o[6] = f2bf_rne(b.z); o[7] = f2bf_rne(b.w);
      d8[i] = o;
    }
    return;
  }
  // ---- router
  const int wid  = threadIdx.x >> 6;
  const int lane = threadIdx.x & 63;
  const int t = blockIdx.x * 4 + wid;

  const float4* xr = (const float4*)(x + (size_t)t * HD);
  const float4* g4 = (const float4*)gw;
  ushort4* xb4 = (ushort4*)(xb + (size_t)t * HD);

  float acc[NE];
#pragma unroll
  for (int e = 0; e < NE; ++e) acc[e] = 0.f;

#pragma unroll
  for (int it = 0; it < 8; ++it) {
    int idx = it * 64 + lane;
    float4 v = xr[idx];
    ushort4 o;
    o.x = f2bf_rne(v.x); o.y = f2bf_rne(v.y);
    o.z = f2bf_rne(v.z); o.w = f2bf_rne(v.w);
    xb4[idx] = o;
#pragma unroll
    for (int e = 0; e < NE; ++e) {
      float4 g = g4[e * 512 + idx];
      acc[e] += v.x * g.x + v.y * g.y + v.z * g.z + v.w * g.w;
    }
  }
#pragma unroll
  for (int e = 0; e < NE; ++e) {
#pragma unroll
    for (int off = 32; off > 0; off >>= 1)
      acc[e] += __shfl_xor(acc[e], off, 64);
  }
  if (lane == 0) {
    float* lo = logits_out + (size_t)t * NE;
#pragma unroll
    for (int e = 0; e < NE; ++e) lo[e] = acc[e];
    // top-2 (exact fp32 math, same as verified rounds)
    int i0 = 0; float b0 = acc[0];
#pragma unroll
    for (int k = 1; k < NE; ++k) if (acc[k] > b0) { b0 = acc[k]; i0 = k; }
    int i1 = -1; float b1 = -3.4e38f;
#pragma unroll
    for (int k = 0; k < NE; ++k) if (k != i0 && acc[k] > b1) { b1 = acc[k]; i1 = k; }
    float w0 = 1.f / (1.f + __expf(b1 - b0));
    float w1 = 1.f - w0;
    int a  = i0 < i1 ? i0 : i1;
    int b  = i0 < i1 ? i1 : i0;
    float wa = i0 < i1 ? w0 : w1;
    float wbv = i0 < i1 ? w1 : w0;
    int p = a * (13 - a) / 2 + b - 1;
    int pos = atomicAdd(&counts[p * 32], 1);
    btok[p * PCAP + pos] = t;
    bw2 [p * PCAP + pos] = make_float2(wa, wbv);
  }
}

// ---------------------------------------------------------------- MoE GEMM
// PAIR-bucketed: block = (pair, rowtile of 128 tokens, coltile of 128 cols).
// Stages A once + BOTH experts' W panels (48KB LDS), 32 MFMA/K-step, and
// writes the FINAL fp32 row (w_a*accA + w_b*accB) — no combine pass, no
// slot1 buffer, each (token, col) written by exactly one block.
__global__ __launch_bounds__(256, 2) void moe_gemm_kernel(
    const unsigned short* __restrict__ xb,
    const unsigned short* __restrict__ wb,
    const int* __restrict__ counts,
    const int* __restrict__ btok,
    const float2* __restrict__ bw2,
    float* __restrict__ out) {
  const int d = blockIdx.x;
  const int p = d >> 8;           // 28 pairs x 256 blocks (16 r x 16 c)
  const int r = (d >> 4) & 15;
  const int c = d & 15;
  const int cnt = counts[p * 32];
  if (r * 128 >= cnt) return;
  const int ea = d_pa[p], eb = d_pb[p];

  __shared__ unsigned short As [128 * 64];   // 16 KB
  __shared__ unsigned short B0s[128 * 64];   // 16 KB
  __shared__ unsigned short B1s[128 * 64];   // 16 KB

  const int tid  = threadIdx.x;
  const int wid  = tid >> 6;
  const int lane = tid & 63;

  // staging: 1024 16B slots per tile; LDS slot(row,ps) holds chunk ps^(row&7)
  int a_off[4], b0_off[4], b1_off[4];
#pragma unroll
  for (int it = 0; it < 4; ++it) {
    int slot = wid * 256 + it * 64 + lane;
    int row  = slot >> 3;
    int ch   = (slot & 7) ^ (row & 7);
    int rc   = r * 128 + row;
    rc = rc < cnt ? rc : cnt - 1;            // clamp pad rows
    a_off[it]  = btok[p * PCAP + rc] * HD + ch * 8;
    b0_off[it] = (ea * HD + c * 128 + row) * HD + ch * 8;
    b1_off[it] = (eb * HD + c * 128 + row) * HD + ch * 8;
  }

  f32x16 accA[2][2], accB[2][2];
#pragma unroll
  for (int i = 0; i < 2; ++i)
#pragma unroll
    for (int j = 0; j < 2; ++j)
#pragma unroll
      for (int g = 0; g < 16; ++g) { accA[i][j][g] = 0.f; accB[i][j][g] = 0.f; }

  const int l5  = lane >> 5;   // k-half
  const int ln  = lane & 31;   // m/n within 32-tile
  const int wm2 = wid >> 1;
  const int wn2 = wid & 1;

  int a_rd[2][4], b_rd[2][4];
#pragma unroll
  for (int t = 0; t < 2; ++t)
#pragma unroll
    for (int kc = 0; kc < 4; ++kc) {
      int ra = wm2 * 64 + t * 32 + ln;
      a_rd[t][kc] = ra * 64 + ((kc * 2 + l5) ^ (ra & 7)) * 8;
      int rb = wn2 * 64 + t * 32 + ln;
      b_rd[t][kc] = rb * 64 + ((kc * 2 + l5) ^ (rb & 7)) * 8;
    }

  for (int k0 = 0; k0 < HD; k0 += 64) {
#pragma unroll
    for (int it = 0; it < 4; ++it) {
      int lb = (wid * 256 + it * 64) * 8;
      async_load16(xb + a_off[it]  + k0, &As [lb]);
      async_load16(wb + b0_off[it] + k0, &B0s[lb]);
      async_load16(wb + b1_off[it] + k0, &B1s[lb]);
    }
    __syncthreads();
#pragma unroll
    for (int kc = 0; kc < 4; ++kc) {
      short8 a0 = *(const short8*)&As[a_rd[0][kc]];
      short8 a1 = *(const short8*)&As[a_rd[1][kc]];
      short8 f0 = *(const short8*)&B0s[b_rd[0][kc]];
      short8 f1 = *(const short8*)&B0s[b_rd[1][kc]];
      accA[0][0] = __builtin_amdgcn_mfma_f32_32x32x16_bf16(a0, f0, accA[0][0], 0, 0, 0);
      accA[0][1] = __builtin_amdgcn_mfma_f32_32x32x16_bf16(a0, f1, accA[0][1], 0, 0, 0);
      accA[1][0] = __builtin_amdgcn_mfma_f32_32x32x16_bf16(a1, f0, accA[1][0], 0, 0, 0);
      accA[1][1] = __builtin_amdgcn_mfma_f32_32x32x16_bf16(a1, f1, accA[1][1], 0, 0, 0);
      short8 g0 = *(const short8*)&B1s[b_rd[0][kc]];
      short8 g1 = *(const short8*)&B1s[b_rd[1][kc]];
      accB[0][0] = __builtin_amdgcn_mfma_f32_32x32x16_bf16(a0, g0, accB[0][0], 0, 0, 0);
      accB[0][1] = __builtin_amdgcn_mfma_f32_32x32x16_bf16(a0, g1, accB[0][1], 0, 0, 0);
      accB[1][0] = __builtin_amdgcn_mfma_f32_32x32x16_bf16(a1, g0, accB[1][0], 0, 0, 0);
      accB[1][1] = __builtin_amdgcn_mfma_f32_32x32x16_bf16(a1, g1, accB[1][1], 0, 0, 0);
    }
    __syncthreads();
  }

  // epilogue: C/D layout col=lane&31, row=(reg&3)+8*(reg>>2)+4*(lane>>5)
  // final value = wa*accA + wb*accB, single fp32 write.
#pragma unroll
  for (int ti = 0; ti < 2; ++ti)
#pragma unroll
    for (int rg = 0; rg < 16; ++rg) {
      int row = (rg & 3) + 8 * (rg >> 2) + 4 * l5;
      int gm  = r * 128 + wm2 * 64 + ti * 32 + row;
      if (gm < cnt) {
        int    tok = btok[p * PCAP + gm];
        float2 w   = bw2 [p * PCAP + gm];
        int    nb  = c * 128 + wn2 * 64 + ln;
        float v0 = w.x * accA[ti][0][rg] + w.y * accB[ti][0][rg];
        float v1 = w.x * accA[ti][1][rg] + w.y * accB[ti][1][rg];
        float* orow = out + (size_t)tok * HD + nb;
        orow[0]  = v0;
        orow[32] = v1;
      }
    }
}

// ---------------------------------------------------------------- launch
extern "C" void kernel_launch(void* const* d_in, const int* in_sizes, int n_in,
                              void* d_out, int out_size, void* d_ws, size_t ws_size,
                              hipStream_t stream) {
  const float* x  = (const float*)d_in[0];   // [8192, 2048]
  const float* gw = (const float*)d_in[1];   // [8, 2048]
  const float* ew = (const float*)d_in[2];   // [8, 2048, 2048]
  float* out = (float*)d_out;                // [8192*2048] ++ [8192*8]

  char* ws = (char*)d_ws;
  unsigned short* xb   = (unsigned short*)ws;                   // 33,554,432 B
  unsigned short* wb   = (unsigned short*)(ws + 33554432u);     // 67,108,864 B
  int*    btok   = (int*)   (ws + 100663296u);                  // 917,504 B
  float2* bw2    = (float2*)(ws + 101580800u);                  // 1,835,008 B
  int*    counts = (int*)   (ws + 103415808u);                  // 3,584 B

  float* logits = out + (size_t)TOKENS * HD;

  hipMemsetAsync(counts, 0, NP * 32 * sizeof(int), stream);
  prep_kernel<<<6144, 256, 0, stream>>>(x, gw, ew, xb, wb, logits,
                                        counts, btok, bw2);
  moe_gemm_kernel<<<NP * 256, 256, 0, stream>>>(xb, wb, counts, btok, bw2, out);
}

// Round 5
// 498.667 us; speedup vs baseline: 1.0706x; 1.0706x over previous
//
#include <hip/hip_runtime.h>
#include <hip/hip_bf16.h>
#include <stdint.h>

#define TOKENS 8192
#define HD     2048
#define NE     8

typedef __attribute__((ext_vector_type(8)))  short short8;
typedef __attribute__((ext_vector_type(8)))  unsigned short ushort8v;
typedef __attribute__((ext_vector_type(16))) float f32x16;

__device__ __forceinline__ unsigned short f2bf_rne(float f) {
  union { float f; unsigned u; } v; v.f = f;
  unsigned u = v.u;
  return (unsigned short)((u + 0x7fffu + ((u >> 16) & 1u)) >> 16);
}

__device__ __forceinline__ void async_load16(const void* g, void* lds) {
  __builtin_amdgcn_global_load_lds(
      (const __attribute__((address_space(1))) unsigned int*)g,
      (__attribute__((address_space(3))) unsigned int*)lds, 16, 0, 0);
}

// ---------------------------------------------------------------- prep
// blocks 0..2047 = router (wave-per-token fp32 logits + x->bf16),
// blocks 2048..6143 = expert-W fp32->bf16 convert. No atomics here
// (per-token atomics measured +20us in round 3 — bucketing is a separate
// ballot-aggregated kernel).
__global__ __launch_bounds__(256) void prep_kernel(
    const float* __restrict__ x, const float* __restrict__ gw,
    const float* __restrict__ ew, unsigned short* __restrict__ xb,
    unsigned short* __restrict__ wb, float* __restrict__ logits_out) {
  if (blockIdx.x >= 2048) {
    // ---- convert W: 4 iters/thread over 4,194,304 ushort8 units
    int i = (blockIdx.x - 2048) * 256 + threadIdx.x;
    const int n8 = NE * HD * HD / 8;
    const int stride = 4096 * 256;
    const float4* s4 = (const float4*)ew;
    ushort8v* d8 = (ushort8v*)wb;
    for (; i < n8; i += stride) {
      float4 a = s4[i * 2], b = s4[i * 2 + 1];
      ushort8v o;
      o[0] = f2bf_rne(a.x); o[1] = f2bf_rne(a.y);
      o[2] = f2bf_rne(a.z); o[3] = f2bf_rne(a.w);
      o[4] = f2bf_rne(b.x); o[5] = f2bf_rne(b.y);
      o[6] = f2bf_rne(b.z); o[7] = f2bf_rne(b.w);
      d8[i] = o;
    }
    return;
  }
  // ---- router
  const int wid  = threadIdx.x >> 6;
  const int lane = threadIdx.x & 63;
  const int t = blockIdx.x * 4 + wid;

  const float4* xr = (const float4*)(x + (size_t)t * HD);
  const float4* g4 = (const float4*)gw;
  ushort4* xb4 = (ushort4*)(xb + (size_t)t * HD);

  float acc[NE];
#pragma unroll
  for (int e = 0; e < NE; ++e) acc[e] = 0.f;

#pragma unroll
  for (int it = 0; it < 8; ++it) {
    int idx = it * 64 + lane;
    float4 v = xr[idx];
    ushort4 o;
    o.x = f2bf_rne(v.x); o.y = f2bf_rne(v.y);
    o.z = f2bf_rne(v.z); o.w = f2bf_rne(v.w);
    xb4[idx] = o;
#pragma unroll
    for (int e = 0; e < NE; ++e) {
      float4 g = g4[e * 512 + idx];
      acc[e] += v.x * g.x + v.y * g.y + v.z * g.z + v.w * g.w;
    }
  }
#pragma unroll
  for (int e = 0; e < NE; ++e) {
#pragma unroll
    for (int off = 32; off > 0; off >>= 1)
      acc[e] += __shfl_xor(acc[e], off, 64);
  }
  if (lane == 0) {
    float* lo = logits_out + (size_t)t * NE;
#pragma unroll
    for (int e = 0; e < NE; ++e) lo[e] = acc[e];
  }
}

// ---------------------------------------------------------------- bucket
// 256 blocks = 8 experts x 32 strips of 256 tokens. Slot-merged (atomic
// epilogue makes primary/secondary symmetric): one ballot + one atomic per
// wave. ~1024 atomics total over 8 spread cache lines.
__global__ __launch_bounds__(256) void bucket_kernel(
    const float* __restrict__ logits, int* __restrict__ counts,
    int* __restrict__ btok, float* __restrict__ bwt) {
  const int e = blockIdx.x & 7;
  const int t = (blockIdx.x >> 3) * 256 + threadIdx.x;
  const int lane = threadIdx.x & 63;

  const float4* lo4 = (const float4*)(logits + (size_t)t * NE);
  float4 la = lo4[0], lb = lo4[1];
  float l[NE] = {la.x, la.y, la.z, la.w, lb.x, lb.y, lb.z, lb.w};
  int i0 = 0; float b0 = l[0];
#pragma unroll
  for (int k = 1; k < NE; ++k) if (l[k] > b0) { b0 = l[k]; i0 = k; }
  int i1 = -1; float b1 = -3.4e38f;
#pragma unroll
  for (int k = 0; k < NE; ++k) if (k != i0 && l[k] > b1) { b1 = l[k]; i1 = k; }
  float w0 = 1.f / (1.f + __expf(b1 - b0));
  float w1 = 1.f - w0;

  bool  p = (i0 == e) || (i1 == e);
  float w = (i0 == e) ? w0 : w1;
  unsigned long long mask = __ballot(p);
  int prefix = __popcll(mask & ((1ull << lane) - 1ull));
  int tot    = __popcll(mask);
  int base = 0;
  if (lane == 0 && tot) base = atomicAdd(&counts[e * 32], tot);
  base = __shfl(base, 0, 64);
  if (p) {
    btok[e * TOKENS + base + prefix] = t;
    bwt [e * TOKENS + base + prefix] = w;
  }
}

// ---------------------------------------------------------------- MoE GEMM
// Verified round-1/3 core (189us / 744 TF): 32KB LDS single-buffer, async
// global_load_lds 16B, XOR swizzle, mfma_f32_32x32x16_bf16 2x2 frags/wave,
// __syncthreads. NEW epilogue: weighted fp32 atomicAdd into pre-zeroed out
// for BOTH top-2 slots — combine kernel + slot1 buffer deleted. Two fp32
// adds onto 0 are order-independent bit-exact.
__global__ __launch_bounds__(256, 4) void moe_gemm_kernel(
    const unsigned short* __restrict__ xb,
    const unsigned short* __restrict__ wb,
    const int* __restrict__ counts,
    const int* __restrict__ btok,
    const float* __restrict__ bwt,
    float* __restrict__ out) {
  int d = blockIdx.x;
  int e, coltile, rowtile;
  if (d < 2048) {
    e       = d & 7;          // XCD affinity (dispatch round-robins % 8)
    rowtile = (d >> 3) & 15;
    coltile = d >> 7;
  } else {
    int u = d - 2048;         // overflow: experts with 2048 < cnt <= 4096
    e       = u & 7;
    coltile = (u & 127) >> 3;
    rowtile = 16 + (u >> 7);
  }
  const int cnt = counts[e * 32];
  if (rowtile * 128 >= cnt) return;

  __shared__ unsigned short As[128 * 64];   // 16 KB
  __shared__ unsigned short Bs[128 * 64];   // 16 KB

  const int tid  = threadIdx.x;
  const int wid  = tid >> 6;
  const int lane = tid & 63;

  // staging: 1024 16B slots/tile; LDS slot(row,p) holds chunk p^(row&7)
  int a_off[4], b_off[4];
#pragma unroll
  for (int it = 0; it < 4; ++it) {
    int slot = wid * 256 + it * 64 + lane;
    int row  = slot >> 3;
    int ch   = (slot & 7) ^ (row & 7);
    int rc   = rowtile * 128 + row;
    rc = rc < cnt ? rc : cnt - 1;            // clamp pad rows
    a_off[it] = btok[e * TOKENS + rc] * HD + ch * 8;
    b_off[it] = (e * HD + coltile * 128 + row) * HD + ch * 8;
  }

  f32x16 acc[2][2];
#pragma unroll
  for (int i = 0; i < 2; ++i)
#pragma unroll
    for (int j = 0; j < 2; ++j)
#pragma unroll
      for (int r = 0; r < 16; ++r) acc[i][j][r] = 0.f;

  const int l5  = lane >> 5;   // k-half
  const int ln  = lane & 31;   // m/n within 32-tile
  const int wm2 = wid >> 1;
  const int wn2 = wid & 1;

  // fragment read offsets: A[m][k]: m=ln, k=(l5)*8+j within K-chunk kc*16
  int a_rd[2][4], b_rd[2][4];
#pragma unroll
  for (int t = 0; t < 2; ++t)
#pragma unroll
    for (int kc = 0; kc < 4; ++kc) {
      int ra = wm2 * 64 + t * 32 + ln;
      a_rd[t][kc] = ra * 64 + ((kc * 2 + l5) ^ (ra & 7)) * 8;
      int rb = wn2 * 64 + t * 32 + ln;
      b_rd[t][kc] = rb * 64 + ((kc * 2 + l5) ^ (rb & 7)) * 8;
    }

  for (int k0 = 0; k0 < HD; k0 += 64) {
#pragma unroll
    for (int it = 0; it < 4; ++it) {
      async_load16(xb + a_off[it] + k0, &As[(wid * 256 + it * 64) * 8]);
      async_load16(wb + b_off[it] + k0, &Bs[(wid * 256 + it * 64) * 8]);
    }
    __syncthreads();
    short8 fa[2][4], fb[2][4];
#pragma unroll
    for (int t = 0; t < 2; ++t)
#pragma unroll
      for (int kc = 0; kc < 4; ++kc) {
        fa[t][kc] = *(const short8*)&As[a_rd[t][kc]];
        fb[t][kc] = *(const short8*)&Bs[b_rd[t][kc]];
      }
#pragma unroll
    for (int kc = 0; kc < 4; ++kc)
#pragma unroll
      for (int i = 0; i < 2; ++i)
#pragma unroll
        for (int j = 0; j < 2; ++j)
          acc[i][j] = __builtin_amdgcn_mfma_f32_32x32x16_bf16(
              fa[i][kc], fb[j][kc], acc[i][j], 0, 0, 0);
    __syncthreads();
  }

  // epilogue: 32x32 C/D layout col=lane&31, row=(reg&3)+8*(reg>>2)+4*(lane>>5)
  // (m74/m101). Weighted atomicAdd for both slots (out pre-zeroed).
#pragma unroll
  for (int ti = 0; ti < 2; ++ti)
#pragma unroll
    for (int rg = 0; rg < 16; ++rg) {
      int row = (rg & 3) + 8 * (rg >> 2) + 4 * l5;
      int gm  = rowtile * 128 + wm2 * 64 + ti * 32 + row;
      if (gm < cnt) {
        int   tok = btok[e * TOKENS + gm];
        float w   = bwt [e * TOKENS + gm];
        int   nb  = coltile * 128 + wn2 * 64 + ln;
        float* orow = out + (size_t)tok * HD + nb;
        atomicAdd(&orow[0],  w * acc[ti][0][rg]);
        atomicAdd(&orow[32], w * acc[ti][1][rg]);
      }
    }
}

// ---------------------------------------------------------------- launch
extern "C" void kernel_launch(void* const* d_in, const int* in_sizes, int n_in,
                              void* d_out, int out_size, void* d_ws, size_t ws_size,
                              hipStream_t stream) {
  const float* x  = (const float*)d_in[0];   // [8192, 2048]
  const float* gw = (const float*)d_in[1];   // [8, 2048]
  const float* ew = (const float*)d_in[2];   // [8, 2048, 2048]
  float* out = (float*)d_out;                // [8192*2048] ++ [8192*8]

  char* ws = (char*)d_ws;
  unsigned short* xb   = (unsigned short*)ws;                   // 33,554,432 B
  unsigned short* wb   = (unsigned short*)(ws + 33554432u);     // 67,108,864 B
  int*   btok   = (int*)  (ws + 100663296u);                    // 262,144 B
  float* bwt    = (float*)(ws + 100925440u);                    // 262,144 B
  int*   counts = (int*)  (ws + 101187584u);                    // 1,024 B

  float* logits = out + (size_t)TOKENS * HD;

  hipMemsetAsync(out, 0, (size_t)TOKENS * HD * sizeof(float), stream);
  hipMemsetAsync(counts, 0, 1024, stream);
  prep_kernel<<<6144, 256, 0, stream>>>(x, gw, ew, xb, wb, logits);
  bucket_kernel<<<256, 256, 0, stream>>>(logits, counts, btok, bwt);
  moe_gemm_kernel<<<4096, 256, 0, stream>>>(xb, wb, counts, btok, bwt, out);
}